// Round 8
// baseline (3555.718 us; speedup 1.0000x reference)
//
#include <hip/hip_runtime.h>

#define T_LEN 2048
#define BATCH 64
#define IN_DIM 50
#define HID 100
#define NTAGS 6

__device__ __forceinline__ float sigf(float x) { return 1.0f / (1.0f + expf(-x)); }

// quad_perm DPP xor-adds (lanes 4u..4u+3 form one unit's chunk quad)
__device__ __forceinline__ float dpp_xor1(float x) {
    int v = __builtin_amdgcn_update_dpp(0, __float_as_int(x), 0xB1, 0xF, 0xF, true);
    return __int_as_float(v);
}
__device__ __forceinline__ float dpp_xor2(float x) {
    int v = __builtin_amdgcn_update_dpp(0, __float_as_int(x), 0x4E, 0xF, 0xF, true);
    return __int_as_float(v);
}

// One workgroup per (batch, direction). 512 threads.
// amdgpu_waves_per_eu(2,2): occupancy capped AND floored at 2 waves/EU (8 waves =
// 1 block/CU) -> VGPR budget 256/thread; the 152 weight floats stay resident.
// (R5 evidence: VGPR_Count=112 -> weights spilled -> L2-BW-bound ~3100 cy/step.)
__global__ __attribute__((amdgpu_flat_work_group_size(512, 512), amdgpu_waves_per_eu(2, 2)))
void lstm_kernel(const float* __restrict__ x,
                 const float* __restrict__ w_ih_f, const float* __restrict__ w_hh_f,
                 const float* __restrict__ b_ih_f, const float* __restrict__ b_hh_f,
                 const float* __restrict__ w_ih_b, const float* __restrict__ w_hh_b,
                 const float* __restrict__ b_ih_b, const float* __restrict__ b_hh_b,
                 const float* __restrict__ w_tag,
                 float* __restrict__ e_f, float* __restrict__ e_b)
{
    __shared__ __align__(16) float h_ch[2][4][28];  // chunked, padded stride 28
    __shared__ __align__(16) float h_flat[2][HID];  // flat copy for emission workers
    __shared__ __align__(16) float xb[2][4][16];    // x chunked: chunk c holds x[13c..13c+12]

    const int tid = threadIdx.x;
    const int b   = blockIdx.x & 63;
    const int dir = blockIdx.x >> 6;

    const float* wih_p = dir ? w_ih_b : w_ih_f;
    const float* whh_p = dir ? w_hh_b : w_hh_f;
    const float* bih_p = dir ? b_ih_b : b_ih_f;
    const float* bhh_p = dir ? b_hh_b : b_hh_f;
    float* e_p = dir ? e_b : e_f;

    // ---- zero ALL of h_ch, h_flat, xb (garbage*0-weight can still be NaN) ----
    {
        float* z1 = &h_ch[0][0][0];    // 224 floats
        if (tid < 224) z1[tid] = 0.0f;
        float* z3 = &xb[0][0][0];      // 128 floats (double-duty lanes)
        if (tid < 128) z3[tid] = 0.0f;
        float* z2 = &h_flat[0][0];     // 200 floats
        if (tid >= 224 && tid < 424) z2[tid - 224] = 0.0f;
    }
    __syncthreads();

    // ---- per-thread setup ----
    const int u = tid >> 2;               // unit 0..99 (valid when tid<400)
    const int c = tid & 3;                // chunk 0..3
    const int uc = u / 25, uo = u % 25;   // h_ch write slot for this unit

    float wx[4][13];
    float wh[4][25];
    float bias4[4];
    if (tid < 400) {
        #pragma unroll
        for (int g = 0; g < 4; ++g) {
            const int row = g * HID + u;
            const float* wri = wih_p + row * IN_DIM;
            #pragma unroll
            for (int m = 0; m < 13; ++m) {
                int i = c * 13 + m;
                wx[g][m] = (i < IN_DIM) ? wri[i] : 0.0f;
            }
            const float* wrh = whh_p + row * HID;
            #pragma unroll
            for (int m = 0; m < 25; ++m) wh[g][m] = wrh[c * 25 + m];
            bias4[g] = bih_p[row] + bhh_p[row];
        }
    }

    const int cw   = tid - 448;                   // emission worker id 0..47
    const int cg   = (cw >= 0) ? (cw >> 3) : 0;   // tag 0..5
    const int cseg = (cw >= 0) ? (cw & 7) : 0;    // segment 0..7 (13 u's each)
    const int u0   = cseg * 13;
    float wt[13];
    if (cw >= 0 && cw < 48) {
        #pragma unroll
        for (int m = 0; m < 13; ++m) {
            int uu = u0 + m;
            wt[m] = (uu < HID) ? w_tag[cg * 200 + dir * HID + uu] : 0.0f;
        }
    }

    // initial x load
    const int t0 = dir ? (T_LEN - 1) : 0;
    if (tid < IN_DIM) xb[0][tid / 13][tid % 13] = x[(t0 * BATCH + b) * IN_DIM + tid];
    __syncthreads();

    float c_reg = 0.0f;
    int cur = 0;
    for (int step = 0; step < T_LEN; ++step) {
        const int t = dir ? (T_LEN - 1 - step) : step;
        const int nxt = cur ^ 1;
        if (tid < 400) {
            // x chunk (13 values, vectorized)
            float4 xq0 = *(const float4*)&xb[cur][c][0];
            float4 xq1 = *(const float4*)&xb[cur][c][4];
            float4 xq2 = *(const float4*)&xb[cur][c][8];
            float x12  = xb[cur][c][12];
            float p0 = 0.f, p1 = 0.f, p2 = 0.f, p3 = 0.f;
            {
                float xv[13] = {xq0.x,xq0.y,xq0.z,xq0.w, xq1.x,xq1.y,xq1.z,xq1.w,
                                xq2.x,xq2.y,xq2.z,xq2.w, x12};
                #pragma unroll
                for (int m = 0; m < 13; ++m) {
                    p0 += xv[m] * wx[0][m];
                    p1 += xv[m] * wx[1][m];
                    p2 += xv[m] * wx[2][m];
                    p3 += xv[m] * wx[3][m];
                }
            }
            // h chunk (25 values): 6 x float4 + 1 scalar, short live ranges
            #pragma unroll
            for (int mb = 0; mb < 6; ++mb) {
                float4 hq = *(const float4*)&h_ch[cur][c][mb * 4];
                float hv[4] = {hq.x, hq.y, hq.z, hq.w};
                #pragma unroll
                for (int l = 0; l < 4; ++l) {
                    p0 += hv[l] * wh[0][mb * 4 + l];
                    p1 += hv[l] * wh[1][mb * 4 + l];
                    p2 += hv[l] * wh[2][mb * 4 + l];
                    p3 += hv[l] * wh[3][mb * 4 + l];
                }
            }
            {
                float h24 = h_ch[cur][c][24];
                p0 += h24 * wh[0][24];
                p1 += h24 * wh[1][24];
                p2 += h24 * wh[2][24];
                p3 += h24 * wh[3][24];
            }
            // cross-chunk quad reduce (DPP): every lane of the quad gets full sums
            p0 += dpp_xor1(p0); p0 += dpp_xor2(p0);
            p1 += dpp_xor1(p1); p1 += dpp_xor2(p1);
            p2 += dpp_xor1(p2); p2 += dpp_xor2(p2);
            p3 += dpp_xor1(p3); p3 += dpp_xor2(p3);
            const float gi = p0 + bias4[0];
            const float gf = p1 + bias4[1];
            const float gg = p2 + bias4[2];
            const float go = p3 + bias4[3];
            c_reg = sigf(gf) * c_reg + sigf(gi) * tanhf(gg);
            const float h = sigf(go) * tanhf(c_reg);
            if (c == 0) {
                h_ch[nxt][uc][uo] = h;
                h_flat[nxt][u]    = h;
            }
        } else if (cw >= 0 && cw < 48) {
            if (step > 0) {  // emission for the PREVIOUS step's h (in h_flat[cur])
                const int tp = dir ? (t + 1) : (t - 1);
                float p = 0.f;
                #pragma unroll
                for (int m = 0; m < 13; ++m) {
                    int uu = u0 + m;
                    if (uu < HID) p += h_flat[cur][uu] * wt[m];
                }
                p += __shfl_xor(p, 1);
                p += __shfl_xor(p, 2);
                p += __shfl_xor(p, 4);
                if (cseg == 0) e_p[(tp * BATCH + b) * NTAGS + cg] = p;
            }
        } else if (tid >= 496) {
            const int tn = dir ? (t - 1) : (t + 1);
            if (tn >= 0 && tn < T_LEN) {
                const int li = tid - 496;
                #pragma unroll
                for (int m = 0; m < 4; ++m) {
                    int i = li + 16 * m;
                    if (i < IN_DIM) xb[nxt][i / 13][i % 13] = x[(tn * BATCH + b) * IN_DIM + i];
                }
            }
        }
        __syncthreads();
        cur = nxt;
    }
    // emission for the final step's h
    if (cw >= 0 && cw < 48) {
        const int tp = dir ? 0 : (T_LEN - 1);
        float p = 0.f;
        #pragma unroll
        for (int m = 0; m < 13; ++m) {
            int uu = u0 + m;
            if (uu < HID) p += h_flat[cur][uu] * wt[m];
        }
        p += __shfl_xor(p, 1);
        p += __shfl_xor(p, 2);
        p += __shfl_xor(p, 4);
        if (cseg == 0) e_p[(tp * BATCH + b) * NTAGS + cg] = p;
    }
}

// Single wave, lane = batch. Scan entirely in registers (no cross-lane ops);
// backpointers (6 tags x 3 bits = u32) stashed into out row t-1; backtrace
// reads each row's stash just before overwriting the row with its one-hot.
// fp32 expression tree per scalar identical to the R2/R5-passing code:
// (sc[i]+tr[i][j])+e[j]; argmax = fmax-tree + first-== (equiv. to strict-> scan).
__global__ void viterbi_scan(const float* __restrict__ e_f, const float* __restrict__ e_b,
                             const float* __restrict__ b_tag,
                             const float* __restrict__ start_t, const float* __restrict__ end_t,
                             const float* __restrict__ trans,
                             float* __restrict__ out)
{
    const int b = threadIdx.x;   // 0..63
    const size_t RSTR = (size_t)BATCH * NTAGS;   // floats per time row

    float tr[36];
    #pragma unroll
    for (int m = 0; m < 36; ++m) tr[m] = trans[m];
    float bt[6];
    #pragma unroll
    for (int j = 0; j < 6; ++j) bt[j] = b_tag[j];

    const float* pf = e_f + (size_t)b * NTAGS;
    const float* pb = e_b + (size_t)b * NTAGS;

    float sc[6];

    auto loadrow = [&](int t, float2& F0, float2& F1, float2& F2,
                       float2& B0, float2& B1, float2& B2) {
        const float* rf = pf + (size_t)t * RSTR;
        const float* rb = pb + (size_t)t * RSTR;
        F0 = *(const float2*)(rf);  F1 = *(const float2*)(rf + 2);  F2 = *(const float2*)(rf + 4);
        B0 = *(const float2*)(rb);  B1 = *(const float2*)(rb + 2);  B2 = *(const float2*)(rb + 4);
    };

    auto body = [&](int t, float2 F0, float2 F1, float2 F2,
                    float2 B0, float2 B1, float2 B2) {
        float ef[6] = {F0.x, F0.y, F1.x, F1.y, F2.x, F2.y};
        float eb[6] = {B0.x, B0.y, B1.x, B1.y, B2.x, B2.y};
        unsigned pack = 0;
        float ns[6];
        #pragma unroll
        for (int j = 0; j < 6; ++j) {
            const float ej = (ef[j] + eb[j]) + bt[j];
            float v0 = (sc[0] + tr[0 * 6 + j]) + ej;
            float v1 = (sc[1] + tr[1 * 6 + j]) + ej;
            float v2 = (sc[2] + tr[2 * 6 + j]) + ej;
            float v3 = (sc[3] + tr[3 * 6 + j]) + ej;
            float v4 = (sc[4] + tr[4 * 6 + j]) + ej;
            float v5 = (sc[5] + tr[5 * 6 + j]) + ej;
            float best = fmaxf(fmaxf(fmaxf(v0, v1), fmaxf(v2, v3)), fmaxf(v4, v5));
            int bi = 5;
            bi = (v4 == best) ? 4 : bi;
            bi = (v3 == best) ? 3 : bi;
            bi = (v2 == best) ? 2 : bi;
            bi = (v1 == best) ? 1 : bi;
            bi = (v0 == best) ? 0 : bi;      // first-max wins, = jnp.argmax
            ns[j] = best;
            pack |= (unsigned)bi << (3 * j);
        }
        *(unsigned*)(out + ((size_t)(t - 1) * BATCH + b) * NTAGS) = pack;  // stash bp[t] at row t-1
        #pragma unroll
        for (int j = 0; j < 6; ++j) sc[j] = ns[j];
    };

    // init: sc = start + e[0]
    {
        float2 F0, F1, F2, B0, B1, B2;
        loadrow(0, F0, F1, F2, B0, B1, B2);
        float ef[6] = {F0.x, F0.y, F1.x, F1.y, F2.x, F2.y};
        float eb[6] = {B0.x, B0.y, B1.x, B1.y, B2.x, B2.y};
        #pragma unroll
        for (int j = 0; j < 6; ++j) sc[j] = start_t[j] + ((ef[j] + eb[j]) + bt[j]);
    }

    // double-buffered row prefetch
    float2 fA0, fA1, fA2, bA0, bA1, bA2;
    float2 fB0, fB1, fB2, bB0, bB1, bB2;
    loadrow(1, fA0, fA1, fA2, bA0, bA1, bA2);
    loadrow(2, fB0, fB1, fB2, bB0, bB1, bB2);

    for (int t = 1; t <= T_LEN - 3; t += 2) {
        body(t, fA0, fA1, fA2, bA0, bA1, bA2);
        loadrow(t + 2, fA0, fA1, fA2, bA0, bA1, bA2);
        body(t + 1, fB0, fB1, fB2, bB0, bB1, bB2);
        { int tl = t + 3; if (tl > T_LEN - 1) tl = T_LEN - 1; loadrow(tl, fB0, fB1, fB2, bB0, bB1, bB2); }
    }
    body(T_LEN - 1, fA0, fA1, fA2, bA0, bA1, bA2);

    // final tag: argmax_j (sc[j] + end[j]), first-max (strict >)
    int tag = 0;
    {
        float best = sc[0] + end_t[0];
        #pragma unroll
        for (int j = 1; j < 6; ++j) {
            float v = sc[j] + end_t[j];
            if (v > best) { best = v; tag = j; }
        }
    }

    __threadfence();   // stash stores visible before backtrace loads

    auto writeoh = [&](int t, int tg) {
        float* o = out + ((size_t)t * BATCH + b) * NTAGS;
        o[0] = (tg == 0) ? 1.0f : 0.0f;
        o[1] = (tg == 1) ? 1.0f : 0.0f;
        o[2] = (tg == 2) ? 1.0f : 0.0f;
        o[3] = (tg == 3) ? 1.0f : 0.0f;
        o[4] = (tg == 4) ? 1.0f : 0.0f;
        o[5] = (tg == 5) ? 1.0f : 0.0f;
    };
    auto stash = [&](int r) -> unsigned {
        return *(const unsigned*)(out + ((size_t)r * BATCH + b) * NTAGS);
    };

    writeoh(T_LEN - 1, tag);

    // backtrace rows 2046..0; stash(row r) = bp[r+1] -> tag_r = stash(r)[tag_{r+1}].
    // Loads are data-independent (address = row), pipelined 16-deep, static indices.
    unsigned curw[16], nxtw[16];
    #pragma unroll
    for (int s = 0; s < 16; ++s) curw[s] = stash(2046 - s);

    for (int cb = 2046; cb >= 46; cb -= 16) {
        #pragma unroll
        for (int s = 0; s < 16; ++s) nxtw[s] = stash(cb - 16 - s);
        #pragma unroll
        for (int s = 0; s < 16; ++s) {
            tag = (int)((curw[s] >> (3 * tag)) & 7u);
            writeoh(cb - s, tag);
        }
        #pragma unroll
        for (int s = 0; s < 16; ++s) curw[s] = nxtw[s];
    }
    // rows 30..15 (prefetched by the final loop iteration)
    #pragma unroll
    for (int s = 0; s < 16; ++s) {
        tag = (int)((curw[s] >> (3 * tag)) & 7u);
        writeoh(30 - s, tag);
    }
    // rows 14..0
    unsigned tailw[15];
    #pragma unroll
    for (int s = 0; s < 15; ++s) tailw[s] = stash(14 - s);
    #pragma unroll
    for (int s = 0; s < 15; ++s) {
        tag = (int)((tailw[s] >> (3 * tag)) & 7u);
        writeoh(14 - s, tag);
    }
}

extern "C" void kernel_launch(void* const* d_in, const int* in_sizes, int n_in,
                              void* d_out, int out_size, void* d_ws, size_t ws_size,
                              hipStream_t stream) {
    const float* x       = (const float*)d_in[0];
    const float* w_ih_f  = (const float*)d_in[1];
    const float* w_hh_f  = (const float*)d_in[2];
    const float* b_ih_f  = (const float*)d_in[3];
    const float* b_hh_f  = (const float*)d_in[4];
    const float* w_ih_b  = (const float*)d_in[5];
    const float* w_hh_b  = (const float*)d_in[6];
    const float* b_ih_b  = (const float*)d_in[7];
    const float* b_hh_b  = (const float*)d_in[8];
    const float* w_tag   = (const float*)d_in[9];
    const float* b_tag   = (const float*)d_in[10];
    const float* start_t = (const float*)d_in[11];
    const float* end_t   = (const float*)d_in[12];
    const float* trans   = (const float*)d_in[13];
    float* out = (float*)d_out;

    float* e_f = (float*)d_ws;                         // (T,B,6) fwd emissions, 3 MiB
    float* e_b = e_f + (size_t)T_LEN * BATCH * NTAGS;  // (T,B,6) bwd emissions, 3 MiB

    lstm_kernel<<<dim3(128), dim3(512), 0, stream>>>(
        x, w_ih_f, w_hh_f, b_ih_f, b_hh_f,
        w_ih_b, w_hh_b, b_ih_b, b_hh_b, w_tag, e_f, e_b);

    viterbi_scan<<<dim3(1), dim3(64), 0, stream>>>(
        e_f, e_b, b_tag, start_t, end_t, trans, out);
}